// Round 11
// baseline (74.879 us; speedup 1.0000x reference)
//
#include <hip/hip_runtime.h>

// LocalCrossCorrelation3D: I,J (2,1,96,192,192) fp32 -> (loss[2], cc[2,81,192,192])
// Window (16,9,9): depth valid (96->81), h/w zero-padded +-4.
// K1 = depth sliding sum (regs, prefetched) + two-stage 3+3 w-box in
// fp16-PACKED uint4 LDS (v_cvt_pkrtz pack, v_pk_add_f16 sums, 8 b128/od),
// raw barriers (vmcnt never drained), half2-packed ws (12B/voxel).
// K2 = h sliding box, full unroll + static 8-deep ring + cc + loss.

constexpr int N = 2, D = 96, H = 192, W = 192;
constexpr int OD = 81;            // D - 16 + 1
constexpr int KD = 16;
constexpr int HWp = H * W;        // 36864
constexpr float INV_WIN = 1.0f / 1296.0f;
constexpr float EPS_NZ = 3.0590232050182579e-07f;  // e^-15
constexpr int CH = 24;            // h-chunk per block in K2 (192/24 = 8)
constexpr int ODPB = 14;          // od-range per K1 block (9 blocks/CU)

typedef __fp16 h2 __attribute__((ext_vector_type(2)));

__device__ __forceinline__ unsigned pkrtz(float lo, float hi) {
  h2 h = __builtin_amdgcn_cvt_pkrtz(lo, hi);   // 1 instr: pack 2 f32 -> 2 f16
  unsigned u; __builtin_memcpy(&u, &h, 4); return u;
}
__device__ __forceinline__ h2 as_h2(unsigned u) {
  h2 h; __builtin_memcpy(&h, &u, 4); return h;
}
__device__ __forceinline__ unsigned as_u(h2 h) {
  unsigned u; __builtin_memcpy(&u, &h, 4); return u;
}

// ---------------------------------------------------------------------------
// K1. Per (n,h) row, stream depth with running 5-ch f32 sums; snapshots for
// od and od+1 pack to half2 words {(sI,sJ),(sII,sJJ),(sIJ,0)} in uint4 LDS
// buffers 0/1; one {B1,stage1x2,B2,stage2x2} round serves both. Stage sums
// are packed v_pk_add_f16. Entering/leaving slices for the NEXT pair are
// prefetched during the current round.
// ws layout: [n][odi][h][w] x 3 uints (half2 pairs).
__global__ __launch_bounds__(192)
void k_dw(const float* __restrict__ I, const float* __restrict__ J,
          unsigned* __restrict__ ws, int od0, int c, int odcStride) {
  const int h = blockIdx.x;
  const int n = blockIdx.z;
  const int os = od0 + blockIdx.y * ODPB;
  int oe = od0 + c; if (os + ODPB < oe) oe = os + ODPB;
  if (os >= oe) return;
  const int w = threadIdx.x;

  __shared__ uint4 x4[2][W + 8];
  __shared__ uint4 a4[2][W + 8];

  if (w < 4) {
    x4[0][w] = make_uint4(0u,0u,0u,0u); x4[1][w] = make_uint4(0u,0u,0u,0u);
  }
  if (w >= W - 4) {
    x4[0][w + 8] = make_uint4(0u,0u,0u,0u); x4[1][w + 8] = make_uint4(0u,0u,0u,0u);
  }
  __syncthreads();   // one safe barrier before the pipelined loop

  const size_t colBase = ((size_t)n * D * H + h) * (size_t)W + w;
  const float* Ip = I + colBase;
  const float* Jp = J + colBase;
  unsigned* wbase = ws + ((size_t)n * odcStride * HWp + (size_t)h * W + w) * 3;

  // extra a3 position for halo coverage (pe in 1..3 and 196..198)
  int pe = -1;
  if (w < 3) pe = w + 1;
  else if (w >= W - 3) pe = w + 7;
  const int p = 4 + w;

  // warm-up: accumulate slices [os, os+KD-2] (15 slices)
  float sI = 0.f, sJ = 0.f, sII = 0.f, sJJ = 0.f, sIJ = 0.f;
  for (int d = os; d < os + KD - 1; ++d) {
    const float iv = Ip[(size_t)d * HWp];
    const float jv = Jp[(size_t)d * HWp];
    sI += iv; sJ += jv;
    sII += iv * iv; sJJ += jv * jv; sIJ += iv * jv;
  }

  // prefetch first pair: entering od+15 / od+16, leaving od / od+1
  int od = os;
  float eI0 = Ip[(size_t)(od + KD - 1) * HWp];
  float eJ0 = Jp[(size_t)(od + KD - 1) * HWp];
  float lI0 = Ip[(size_t)od * HWp];
  float lJ0 = Jp[(size_t)od * HWp];
  float eI1 = 0.f, eJ1 = 0.f, lI1 = 0.f, lJ1 = 0.f;
  if (od + 1 < oe) {
    eI1 = Ip[(size_t)(od + KD) * HWp];
    eJ1 = Jp[(size_t)(od + KD) * HWp];
    lI1 = Ip[(size_t)(od + 1) * HWp];
    lJ1 = Jp[(size_t)(od + 1) * HWp];
  }

  while (od < oe) {
    const bool two = (od + 1 < oe);
    const float ceI0 = eI0, ceJ0 = eJ0, clI0 = lI0, clJ0 = lJ0;
    const float ceI1 = eI1, ceJ1 = eJ1, clI1 = lI1, clJ1 = lJ1;
    // prefetch next pair (issued now, awaited next iteration)
    const int odn = od + 2;
    if (odn < oe) {
      eI0 = Ip[(size_t)(odn + KD - 1) * HWp];
      eJ0 = Jp[(size_t)(odn + KD - 1) * HWp];
      lI0 = Ip[(size_t)odn * HWp];
      lJ0 = Jp[(size_t)odn * HWp];
      if (odn + 1 < oe) {
        eI1 = Ip[(size_t)(odn + KD) * HWp];
        eJ1 = Jp[(size_t)(odn + KD) * HWp];
        lI1 = Ip[(size_t)(odn + 1) * HWp];
        lJ1 = Jp[(size_t)(odn + 1) * HWp];
      }
    }
    // snapshot od into buffer 0 (packed)
    sI += ceI0; sJ += ceJ0;
    sII += ceI0 * ceI0; sJJ += ceJ0 * ceJ0; sIJ += ceI0 * ceJ0;
    x4[0][p] = make_uint4(pkrtz(sI, sJ), pkrtz(sII, sJJ), pkrtz(sIJ, 0.f), 0u);
    sI -= clI0; sJ -= clJ0;
    sII -= clI0 * clI0; sJJ -= clJ0 * clJ0; sIJ -= clI0 * clJ0;
    if (two) {  // snapshot od+1 into buffer 1
      sI += ceI1; sJ += ceJ1;
      sII += ceI1 * ceI1; sJJ += ceJ1 * ceJ1; sIJ += ceI1 * ceJ1;
      x4[1][p] = make_uint4(pkrtz(sI, sJ), pkrtz(sII, sJJ), pkrtz(sIJ, 0.f), 0u);
      sI -= clI1; sJ -= clJ1;
      sII -= clI1 * clI1; sJJ -= clJ1 * clJ1; sIJ -= clI1 * clJ1;
    }
    asm volatile("s_waitcnt lgkmcnt(0)" ::: "memory");
    __builtin_amdgcn_s_barrier();       // B1: x[0] (and x[1]) visible
    // stage 1: a3[p] = x[p-1]+x[p]+x[p+1], packed adds, both buffers
    {
      uint4 m0 = x4[0][p - 1], m1 = x4[0][p], m2 = x4[0][p + 1];
      a4[0][p] = make_uint4(as_u(as_h2(m0.x) + as_h2(m1.x) + as_h2(m2.x)),
                            as_u(as_h2(m0.y) + as_h2(m1.y) + as_h2(m2.y)),
                            as_u(as_h2(m0.z) + as_h2(m1.z) + as_h2(m2.z)), 0u);
      if (pe >= 0) {
        uint4 e0 = x4[0][pe - 1], e1 = x4[0][pe], e2 = x4[0][pe + 1];
        a4[0][pe] = make_uint4(as_u(as_h2(e0.x) + as_h2(e1.x) + as_h2(e2.x)),
                               as_u(as_h2(e0.y) + as_h2(e1.y) + as_h2(e2.y)),
                               as_u(as_h2(e0.z) + as_h2(e1.z) + as_h2(e2.z)), 0u);
      }
    }
    if (two) {
      uint4 m0 = x4[1][p - 1], m1 = x4[1][p], m2 = x4[1][p + 1];
      a4[1][p] = make_uint4(as_u(as_h2(m0.x) + as_h2(m1.x) + as_h2(m2.x)),
                            as_u(as_h2(m0.y) + as_h2(m1.y) + as_h2(m2.y)),
                            as_u(as_h2(m0.z) + as_h2(m1.z) + as_h2(m2.z)), 0u);
      if (pe >= 0) {
        uint4 e0 = x4[1][pe - 1], e1 = x4[1][pe], e2 = x4[1][pe + 1];
        a4[1][pe] = make_uint4(as_u(as_h2(e0.x) + as_h2(e1.x) + as_h2(e2.x)),
                               as_u(as_h2(e0.y) + as_h2(e1.y) + as_h2(e2.y)),
                               as_u(as_h2(e0.z) + as_h2(e1.z) + as_h2(e2.z)), 0u);
      }
    }
    asm volatile("s_waitcnt lgkmcnt(0)" ::: "memory");
    __builtin_amdgcn_s_barrier();       // B2: a[0] (and a[1]) visible
    // stage 2: S9 = a3[p-3]+a3[p]+a3[p+3], packed; store half2-packed ws
    {
      uint4 b0 = a4[0][p - 3], b1 = a4[0][p], b2 = a4[0][p + 3];
      unsigned* o = wbase + (size_t)(od - od0) * HWp * 3;
      *(uint3*)o = make_uint3(as_u(as_h2(b0.x) + as_h2(b1.x) + as_h2(b2.x)),
                              as_u(as_h2(b0.y) + as_h2(b1.y) + as_h2(b2.y)),
                              as_u(as_h2(b0.z) + as_h2(b1.z) + as_h2(b2.z)));
    }
    if (two) {
      uint4 b0 = a4[1][p - 3], b1 = a4[1][p], b2 = a4[1][p + 3];
      unsigned* o = wbase + (size_t)(od + 1 - od0) * HWp * 3;
      *(uint3*)o = make_uint3(as_u(as_h2(b0.x) + as_h2(b1.x) + as_h2(b2.x)),
                              as_u(as_h2(b0.y) + as_h2(b1.y) + as_h2(b2.y)),
                              as_u(as_h2(b0.z) + as_h2(b1.z) + as_h2(b2.z)));
    }
    od += 2;
  }
}

// ---------------------------------------------------------------------------
// K2: 9-wide h box via fully-unrolled stream with an 8-deep static ring
// (no subtract re-loads; full unroll -> static indices + deep load pipelining)
// + one-ahead prefetch; cc formula + loss reduction.
// Block: 192 threads = w-row, grid (od, h-chunk of 24, n).
__global__ __launch_bounds__(192)
void k_hcc(const unsigned* __restrict__ ws, float* __restrict__ cc,
           float* __restrict__ acc, int od0, int odcStride) {
  const int odi = blockIdx.x;
  const int od = od0 + odi;
  const int h0 = blockIdx.y * CH;
  const int n = blockIdx.z;
  const int w = threadIdx.x;
  const unsigned* base =
      ws + ((size_t)n * odcStride * HWp + (size_t)odi * HWp + w) * 3;
  float* ccp = cc + ((size_t)n * OD + od) * (size_t)HWp + w;

  float s0 = 0.f, s1 = 0.f, s2 = 0.f, s3 = 0.f, s4 = 0.f;
  float lsum = 0.f;
  uint3 hist[8];
  const uint3 z3 = make_uint3(0u, 0u, 0u);

  // prefetch t=0 row
  uint3 vN = z3;
  {
    const int hin = h0 - 4;
    if (hin >= 0) vN = *(const uint3*)(base + (size_t)hin * W * 3);
  }
#pragma unroll
  for (int t = 0; t < CH + 8; ++t) {
    const uint3 v = vN;
    // prefetch next row
    if (t + 1 < CH + 8) {
      const int hn = h0 - 4 + t + 1;
      vN = (hn >= 0 && hn < H) ? *(const uint3*)(base + (size_t)hn * W * 3) : z3;
    }
    {
      h2 v0 = as_h2(v.x), v1 = as_h2(v.y), v2 = as_h2(v.z);
      s0 += (float)v0[0]; s1 += (float)v0[1];
      s2 += (float)v1[0]; s3 += (float)v1[1];
      s4 += (float)v2[0];
    }
    if (t >= 8) {
      const int h = h0 + t - 8;
      const float cross = s4 - s0 * s1 * INV_WIN;
      const float vI = s2 - s0 * s0 * INV_WIN;
      const float vJ = s3 - s1 * s1 * INV_WIN;
      const float prod = vI * vJ;
      const float c = (prod > EPS_NZ) ? (cross * cross) / (prod + EPS_NZ)
                                      : 1.0f / (1.0f + EPS_NZ);
      ccp[(size_t)h * W] = c;
      lsum += c;
      const uint3 q = hist[t & 7];       // row that entered 8 steps ago
      h2 q0 = as_h2(q.x), q1 = as_h2(q.y), q2 = as_h2(q.z);
      s0 -= (float)q0[0]; s1 -= (float)q0[1];
      s2 -= (float)q1[0]; s3 -= (float)q1[1];
      s4 -= (float)q2[0];
    }
    hist[t & 7] = v;                     // static index (full unroll)
  }
  __shared__ float red[3];
#pragma unroll
  for (int off = 32; off > 0; off >>= 1) lsum += __shfl_xor(lsum, off, 64);
  if ((threadIdx.x & 63) == 0) red[threadIdx.x >> 6] = lsum;
  __syncthreads();
  if (threadIdx.x == 0) atomicAdd(acc + n, red[0] + red[1] + red[2]);
}

// ---------------------------------------------------------------------------
__global__ void k_fin(const float* __restrict__ acc, float* __restrict__ out) {
  if (threadIdx.x < N)
    out[threadIdx.x] = 1.0f - acc[threadIdx.x] * (1.0f / 2985984.0f);
}

// ---------------------------------------------------------------------------
extern "C" void kernel_launch(void* const* d_in, const int* in_sizes, int n_in,
                              void* d_out, int out_size, void* d_ws,
                              size_t ws_size, hipStream_t stream) {
  const float* I = (const float*)d_in[0];
  const float* J = (const float*)d_in[1];
  float* out = (float*)d_out;
  float* acc = (float*)d_ws;                       // 2 fp32 loss accumulators
  unsigned* planes = (unsigned*)((char*)d_ws + 256);

  hipMemsetAsync(d_ws, 0, 2 * sizeof(float), stream);

  // adaptive od-chunking: packed voxel = 12B, two n-slabs
  const size_t perOdPerN = (size_t)HWp * 12;       // 442368 B
  size_t avail = (ws_size > 256) ? (ws_size - 256) : 0;
  long long odcMax = (long long)(avail / (2 * perOdPerN));
  if (odcMax < 1) odcMax = 1;
  if (odcMax > OD) odcMax = OD;
  const int odc = (int)odcMax;                     // slab stride (od entries)

  float* ccOut = out + 2;
  for (int od0 = 0; od0 < OD; od0 += odc) {
    const int c = (odc < OD - od0) ? odc : (OD - od0);
    const int S = (c + ODPB - 1) / ODPB;
    hipLaunchKernelGGL(k_dw, dim3(H, S, N), dim3(192), 0, stream,
                       I, J, planes, od0, c, odc);
    hipLaunchKernelGGL(k_hcc, dim3(c, H / CH, N), dim3(192), 0, stream,
                       planes, ccOut, acc, od0, odc);
  }
  hipLaunchKernelGGL(k_fin, dim3(1), dim3(64), 0, stream, acc, out);
}